// Round 4
// baseline (81.904 us; speedup 1.0000x reference)
//
#include <hip/hip_runtime.h>
#include <math.h>

#define B_TOTAL 8192
#define C_DIM 62
#define CC (C_DIM * C_DIM)   // 3844 floats = 961 float4
#define NB 8                 // batches per block
#define EPSV 1e-4f
#define NSWEEP 6
#define WSTRIDE 72           // per-group exchange stride

// ---------- 8-lane parallel 8x8 Jacobi (XOR tournament ordering) ----------
// Lane e of an 8-lane group owns column e of A and of U (8 regs each).
__device__ __forceinline__ float sel8(const float a[8], int e) {
  float t0 = (e & 4) ? a[4] : a[0];
  float t1 = (e & 4) ? a[5] : a[1];
  float t2 = (e & 4) ? a[6] : a[2];
  float t3 = (e & 4) ? a[7] : a[3];
  float u0 = (e & 2) ? t2 : t0;
  float u1 = (e & 2) ? t3 : t1;
  return (e & 1) ? u1 : u0;
}

__device__ __forceinline__ void jacobi8p(float a[8], float u[8],
                                         const int e, const int base) {
#pragma unroll
  for (int i = 0; i < 8; ++i) u[i] = (i == e) ? 1.f : 0.f;
#pragma unroll 1
  for (int sweep = 0; sweep < NSWEEP; ++sweep) {
#pragma unroll
    for (int m = 1; m < 8; ++m) {
      const int f = e ^ m;
      const bool lower = e < f;
      float diag = sel8(a, e);
      float offd = sel8(a, f);
      float aoth[8], uoth[8];
#pragma unroll
      for (int i = 0; i < 8; ++i) aoth[i] = __shfl_xor(a[i], m);
#pragma unroll
      for (int i = 0; i < 8; ++i) uoth[i] = __shfl_xor(u[i], m);
      float diag_o = __shfl_xor(diag, m);
      float offd_o = __shfl_xor(offd, m);
      // symmetrize apq so both lanes of the pair compute identical (c,s)
      float apq = 0.5f * (offd + offd_o);
      float app = lower ? diag : diag_o;
      float aqq = lower ? diag_o : diag;
      float taun = aqq - app;
      float t = (2.f * apq) * copysignf(1.f, taun) /
                (fabsf(taun) + sqrtf(fmaf(taun, taun, 4.f * apq * apq)) + 1e-38f);
      float c = rsqrtf(fmaf(t, t, 1.f));
      float s = t * c;
      float s2 = lower ? -s : s;
#pragma unroll
      for (int i = 0; i < 8; ++i) a[i] = fmaf(c, a[i], s2 * aoth[i]);
#pragma unroll
      for (int i = 0; i < 8; ++i) u[i] = fmaf(c, u[i], s2 * uoth[i]);
#pragma unroll
      for (int i = 0; i < 8; ++i) {
        const int j = i ^ m;
        if (i < j) {
          float cr = __shfl(c, base | i);
          float sr = __shfl(s, base | i);
          float x = a[i], y = a[j];
          a[i] = fmaf(cr, x, -sr * y);
          a[j] = fmaf(sr, x, cr * y);
        }
      }
    }
  }
}

// ---------------- fused SPDNet kernel ----------------
__global__ __launch_bounds__(256) void spdnet_fused_kernel(
    const float* __restrict__ X, const float* __restrict__ w1,
    const float* __restrict__ w2, const float* __restrict__ fc,
    float* __restrict__ out) {
  __shared__ __align__(16) float Xs[CC];          // 15.4 KB, single buffer
  __shared__ float Ys[C_DIM * 8];                 // 496
  __shared__ float w1s[C_DIM * 8];                // 496
  __shared__ float M1s[NB * 64];                  // 8 batches' 8x8
  __shared__ float w2s[64];
  __shared__ float fcs[128];
  __shared__ __align__(16) float Wbuf[NB * WSTRIDE];
  __shared__ float lwbuf[NB * 8];
  const int tid = threadIdx.x;
  const int b0 = blockIdx.x * NB;

  // stage small weights
  if (tid < 64) w2s[tid] = w2[tid];
  else if (tid < 192) fcs[tid - 64] = fc[tid - 64];
  for (int i = tid; i < C_DIM * 8; i += 256) w1s[i] = w1[i];

  // prefetch batch 0 into registers (regs are the "second buffer")
  float4 r0, r1, r2, r3 = make_float4(0.f, 0.f, 0.f, 0.f);
  {
    const float4* X4 = (const float4*)(X + (size_t)b0 * CC);
    r0 = X4[tid];
    r1 = X4[tid + 256];
    r2 = X4[tid + 512];
    if (tid + 768 < 961) r3 = X4[tid + 768];
  }

  // ---- Phase A: stream X, build M1s in LDS ----
#pragma unroll 1
  for (int t = 0; t < NB; ++t) {
    __syncthreads();                 // Xs/Ys free (previous compute done)
    float4* Xs4 = (float4*)Xs;
    Xs4[tid] = r0;
    Xs4[tid + 256] = r1;
    Xs4[tid + 512] = r2;
    if (tid + 768 < 961) Xs4[tid + 768] = r3;
    __syncthreads();                 // Xs ready (drains only the ds_writes)
    // issue next batch's global loads NOW: they fly under the compute below
    if (t + 1 < NB) {
      const float4* X4 = (const float4*)(X + (size_t)(b0 + t + 1) * CC);
      r0 = X4[tid];
      r1 = X4[tid + 256];
      r2 = X4[tid + 512];
      if (tid + 768 < 961) r3 = X4[tid + 768];
    }
    // Y[c][e] = sum_d X[c][d] * w1[d][e]   (496 items)
#pragma unroll
    for (int rep = 0; rep < 2; ++rep) {
      int i = tid + rep * 256;
      if (i < C_DIM * 8) {
        int c = i >> 3, e = i & 7;
        float acc = 0.f;
#pragma unroll
        for (int d = 0; d < C_DIM; ++d)
          acc = fmaf(Xs[c * C_DIM + d], w1s[d * 8 + e], acc);
        Ys[i] = acc;
      }
    }
    __syncthreads();                 // Ys ready
    // M1[a][e] = sum_c w1[c][a] * Y[c][e]   (64 items, wave 0)
    if (tid < 64) {
      int aa = tid >> 3, e = tid & 7;
      float acc = 0.f;
#pragma unroll
      for (int c = 0; c < C_DIM; ++c)
        acc = fmaf(w1s[c * 8 + aa], Ys[c * 8 + e], acc);
      M1s[t * 64 + tid] = acc;
    }
  }
  __syncthreads();                   // M1s complete

  // ---- Phase B: eig pipeline, 8 lanes per batch (wave 0 active) ----
  const int e = tid & 7;
  const int g = tid >> 3;            // 0..31; only g < NB do work
  const int base = tid & 56;
  const bool act = (tid < NB * 8);   // wave-uniform guard
  const int b = b0 + g;
  float a[8], u[8], v[8], m2[8];
  float* Wg = &Wbuf[(g & (NB - 1)) * WSTRIDE];

  if (act) {
    // load row e of symmetric M1 (= column e)
#pragma unroll
    for (int j = 0; j < 8; ++j) a[j] = M1s[g * 64 + e * 8 + j];
    // ---- eig 1 ----
    jacobi8p(a, u, e, base);
    float lam = sel8(a, e);
    float sw = sqrtf(fmaxf(lam, EPSV));
    // row e of V = U^T w2, scaled by sqrt(clamped eig)
#pragma unroll
    for (int j = 0; j < 8; ++j) v[j] = 0.f;
#pragma unroll
    for (int i = 0; i < 8; ++i)
#pragma unroll
      for (int j = 0; j < 8; ++j) v[j] = fmaf(u[i], w2s[i * 8 + j], v[j]);
#pragma unroll
    for (int j = 0; j < 8; ++j) Wg[e * 8 + j] = v[j] * sw;
  }
  __syncthreads();
  if (act) {
    // M2 column e: m2[i] = sum_k W[k][i] * W[k][e]
    float wcol[8];
#pragma unroll
    for (int k = 0; k < 8; ++k) wcol[k] = Wg[k * 8 + e];
#pragma unroll
    for (int i = 0; i < 8; ++i) m2[i] = 0.f;
#pragma unroll
    for (int k = 0; k < 8; ++k) {
      float4 q0 = *(const float4*)&Wg[k * 8 + 0];
      float4 q1 = *(const float4*)&Wg[k * 8 + 4];
      m2[0] = fmaf(q0.x, wcol[k], m2[0]); m2[1] = fmaf(q0.y, wcol[k], m2[1]);
      m2[2] = fmaf(q0.z, wcol[k], m2[2]); m2[3] = fmaf(q0.w, wcol[k], m2[3]);
      m2[4] = fmaf(q1.x, wcol[k], m2[4]); m2[5] = fmaf(q1.y, wcol[k], m2[5]);
      m2[6] = fmaf(q1.z, wcol[k], m2[6]); m2[7] = fmaf(q1.w, wcol[k], m2[7]);
    }
  }
  __syncthreads();                   // Wbuf reads done before reuse
  if (act) {
    // ---- eig 2 + fused rec+logm ----
#pragma unroll
    for (int i = 0; i < 8; ++i) a[i] = m2[i];
    jacobi8p(a, u, e, base);
    float lw = logf(fmaxf(sel8(a, e), EPSV));
#pragma unroll
    for (int i = 0; i < 8; ++i) Wg[e * 8 + i] = u[i];
    lwbuf[(g & (NB - 1)) * 8 + e] = lw;
  }
  __syncthreads();
  if (act) {
    // feat column e: fcol[i] = sum_k lw_k * T[k][i] * T[k][e]
    float mk[8];
#pragma unroll
    for (int k = 0; k < 8; ++k)
      mk[k] = lwbuf[(g & (NB - 1)) * 8 + k] * Wg[k * 8 + e];
    float fcol[8];
#pragma unroll
    for (int i = 0; i < 8; ++i) fcol[i] = 0.f;
#pragma unroll
    for (int k = 0; k < 8; ++k) {
      float4 q0 = *(const float4*)&Wg[k * 8 + 0];
      float4 q1 = *(const float4*)&Wg[k * 8 + 4];
      fcol[0] = fmaf(q0.x, mk[k], fcol[0]); fcol[1] = fmaf(q0.y, mk[k], fcol[1]);
      fcol[2] = fmaf(q0.z, mk[k], fcol[2]); fcol[3] = fmaf(q0.w, mk[k], fcol[3]);
      fcol[4] = fmaf(q1.x, mk[k], fcol[4]); fcol[5] = fmaf(q1.y, mk[k], fcol[5]);
      fcol[6] = fmaf(q1.z, mk[k], fcol[6]); fcol[7] = fmaf(q1.w, mk[k], fcol[7]);
    }
    float l0 = 0.f, l1 = 0.f;
    float* featg = out + 2 * (size_t)B_TOTAL + (size_t)b * 64;
#pragma unroll
    for (int i = 0; i < 8; ++i) {
      featg[i * 8 + e] = fcol[i];
      l0 = fmaf(fcol[i], fcs[(i * 8 + e) * 2 + 0], l0);
      l1 = fmaf(fcol[i], fcs[(i * 8 + e) * 2 + 1], l1);
    }
#pragma unroll
    for (int mm = 1; mm < 8; mm <<= 1) {
      l0 += __shfl_xor(l0, mm);
      l1 += __shfl_xor(l1, mm);
    }
    float mx = fmaxf(l0, l1);
    float lse = mx + logf(expf(l0 - mx) + expf(l1 - mx));
    if (e < 2) out[(size_t)b * 2 + e] = (e ? l1 : l0) - lse;
  }
}

extern "C" void kernel_launch(void* const* d_in, const int* in_sizes, int n_in,
                              void* d_out, int out_size, void* d_ws, size_t ws_size,
                              hipStream_t stream) {
  const float* X  = (const float*)d_in[0];   // [8192,62,62]
  const float* w1 = (const float*)d_in[1];   // [62,8]
  const float* w2 = (const float*)d_in[2];   // [8,8]
  const float* fc = (const float*)d_in[3];   // [64,2]
  float* out = (float*)d_out;                // [8192*2] ++ [8192*64]

  spdnet_fused_kernel<<<B_TOTAL / NB, 256, 0, stream>>>(X, w1, w2, fc, out);
}

// Round 5
// 70.999 us; speedup vs baseline: 1.1536x; 1.1536x over previous
//
#include <hip/hip_runtime.h>
#include <math.h>

#define B_TOTAL 8192
#define C_DIM 62
#define CC (C_DIM * C_DIM)   // 3844 floats
#define EPSV 1e-4f
#define NSWEEP 6
#define WSTRIDE 72           // per-group exchange stride

// ---------------- Kernel A: M1[b] = w1^T X[b] w1  (62->8) ----------------
// One wave per batch. X staged via global_load_lds (linear dest), Y per-row.
__global__ __launch_bounds__(64) void bimap1_kernel(
    const float* __restrict__ X, const float* __restrict__ w1,
    float* __restrict__ M1) {
  __shared__ __align__(16) float Xs[3856];       // 3844 used
  __shared__ __align__(16) float w1s[C_DIM * 8]; // 496
  __shared__ __align__(16) float Ys[C_DIM * 8];  // 496
  const int lane = threadIdx.x;
  const int b = blockIdx.x;
  const float* Xb = X + (size_t)b * CC;

  // 15 full-wave async chunks: 15 * 64 lanes * 16B = 15360B of 15376B
#pragma unroll
  for (int ch = 0; ch < 15; ++ch) {
    const float* src = Xb + ch * 256 + lane * 4;
    __builtin_amdgcn_global_load_lds(
        (const __attribute__((address_space(1))) unsigned int*)src,
        (__attribute__((address_space(3))) unsigned int*)(Xs + ch * 256),
        16, 0, 0);
  }
  // tail chunk (floats 3840..3843)
  if (lane == 0) *(float4*)(Xs + 3840) = *(const float4*)(Xb + 3840);
  // w1 row c (8 floats, 32B-aligned rows)
  if (lane < C_DIM) {
    *(float4*)(w1s + lane * 8)     = *(const float4*)(w1 + lane * 8);
    *(float4*)(w1s + lane * 8 + 4) = *(const float4*)(w1 + lane * 8 + 4);
  }
  __syncthreads();  // single wave: vmcnt/lgkmcnt drain + trivial barrier

  // Y[c][e] = sum_d X[c][d] * w1[d][e] ; lane c owns row c
  if (lane < C_DIM) {
    float a0=0.f,a1=0.f,a2=0.f,a3=0.f,a4=0.f,a5=0.f,a6=0.f,a7=0.f;
#pragma unroll
    for (int dp = 0; dp < 31; ++dp) {
      float2 x2 = *(const float2*)(Xs + lane * C_DIM + dp * 2); // 8B-aligned
      float4 wA0 = *(const float4*)(w1s + dp * 16);       // row 2dp   e=0..3
      float4 wB0 = *(const float4*)(w1s + dp * 16 + 4);   // row 2dp   e=4..7
      float4 wA1 = *(const float4*)(w1s + dp * 16 + 8);   // row 2dp+1 e=0..3
      float4 wB1 = *(const float4*)(w1s + dp * 16 + 12);  // row 2dp+1 e=4..7
      a0 = fmaf(x2.x, wA0.x, a0); a1 = fmaf(x2.x, wA0.y, a1);
      a2 = fmaf(x2.x, wA0.z, a2); a3 = fmaf(x2.x, wA0.w, a3);
      a4 = fmaf(x2.x, wB0.x, a4); a5 = fmaf(x2.x, wB0.y, a5);
      a6 = fmaf(x2.x, wB0.z, a6); a7 = fmaf(x2.x, wB0.w, a7);
      a0 = fmaf(x2.y, wA1.x, a0); a1 = fmaf(x2.y, wA1.y, a1);
      a2 = fmaf(x2.y, wA1.z, a2); a3 = fmaf(x2.y, wA1.w, a3);
      a4 = fmaf(x2.y, wB1.x, a4); a5 = fmaf(x2.y, wB1.y, a5);
      a6 = fmaf(x2.y, wB1.z, a6); a7 = fmaf(x2.y, wB1.w, a7);
    }
    *(float4*)(Ys + lane * 8)     = make_float4(a0, a1, a2, a3);
    *(float4*)(Ys + lane * 8 + 4) = make_float4(a4, a5, a6, a7);
  }
  __syncthreads();

  // M1[a][e] = sum_c w1[c][a] * Y[c][e] ; lane = (a<<3)|e
  {
    const int a = lane >> 3, e = lane & 7;
    float s = 0.f;
#pragma unroll
    for (int c = 0; c < C_DIM; ++c)
      s = fmaf(w1s[c * 8 + a], Ys[c * 8 + e], s);
    M1[(size_t)b * 64 + lane] = s;
  }
}

// ---------- 8-lane parallel 8x8 Jacobi (XOR tournament ordering) ----------
__device__ __forceinline__ float sel8(const float a[8], int e) {
  float t0 = (e & 4) ? a[4] : a[0];
  float t1 = (e & 4) ? a[5] : a[1];
  float t2 = (e & 4) ? a[6] : a[2];
  float t3 = (e & 4) ? a[7] : a[3];
  float u0 = (e & 2) ? t2 : t0;
  float u1 = (e & 2) ? t3 : t1;
  return (e & 1) ? u1 : u0;
}

__device__ __forceinline__ void jacobi8p(float a[8], float u[8],
                                         const int e, const int base) {
#pragma unroll
  for (int i = 0; i < 8; ++i) u[i] = (i == e) ? 1.f : 0.f;
#pragma unroll 1
  for (int sweep = 0; sweep < NSWEEP; ++sweep) {
#pragma unroll
    for (int m = 1; m < 8; ++m) {
      const int f = e ^ m;
      const bool lower = e < f;
      float diag = sel8(a, e);
      float offd = sel8(a, f);
      float aoth[8], uoth[8];
#pragma unroll
      for (int i = 0; i < 8; ++i) aoth[i] = __shfl_xor(a[i], m);
#pragma unroll
      for (int i = 0; i < 8; ++i) uoth[i] = __shfl_xor(u[i], m);
      float diag_o = __shfl_xor(diag, m);
      float offd_o = __shfl_xor(offd, m);
      // symmetrize apq so both lanes of the pair compute identical (c,s)
      float apq = 0.5f * (offd + offd_o);
      float app = lower ? diag : diag_o;
      float aqq = lower ? diag_o : diag;
      float taun = aqq - app;
      float den = fabsf(taun) + sqrtf(fmaf(taun, taun, 4.f * apq * apq)) + 1e-38f;
      float t = (2.f * apq) * copysignf(1.f, taun) * __builtin_amdgcn_rcpf(den);
      float c = rsqrtf(fmaf(t, t, 1.f));
      float s = t * c;
      float s2 = lower ? -s : s;
#pragma unroll
      for (int i = 0; i < 8; ++i) a[i] = fmaf(c, a[i], s2 * aoth[i]);
#pragma unroll
      for (int i = 0; i < 8; ++i) u[i] = fmaf(c, u[i], s2 * uoth[i]);
#pragma unroll
      for (int i = 0; i < 8; ++i) {
        const int j = i ^ m;
        if (i < j) {
          float cr = __shfl(c, base | i);
          float sr = __shfl(s, base | i);
          float x = a[i], y = a[j];
          a[i] = fmaf(cr, x, -sr * y);
          a[j] = fmaf(sr, x, cr * y);
        }
      }
    }
  }
}

// ---------------- Kernel B: eig pipeline, 1 wave = 8 batches ----------------
__global__ __launch_bounds__(64) void spd_eig8_kernel(
    const float* __restrict__ M1, const float* __restrict__ w2,
    const float* __restrict__ fc, float* __restrict__ out) {
  __shared__ __align__(16) float Wbuf[8 * WSTRIDE];
  __shared__ float lwbuf[64];
  __shared__ float w2s[64];
  __shared__ float fcs[128];
  const int tid = threadIdx.x;      // 0..63
  const int e = tid & 7;
  const int g = tid >> 3;           // 0..7, batch group
  const int base = tid & 56;
  const int b = blockIdx.x * 8 + g;
  w2s[tid] = w2[tid];
  fcs[tid] = fc[tid];
  fcs[tid + 64] = fc[tid + 64];

  float a[8], u[8], v[8], m2[8];
  float* Wg = &Wbuf[g * WSTRIDE];

  // load row e of symmetric M1 (= column e); coalesced 2KB per block
  const float4* m4 = (const float4*)(M1 + (size_t)b * 64 + e * 8);
  float4 v0 = m4[0], v1 = m4[1];
  a[0] = v0.x; a[1] = v0.y; a[2] = v0.z; a[3] = v0.w;
  a[4] = v1.x; a[5] = v1.y; a[6] = v1.z; a[7] = v1.w;
  __syncthreads();  // w2s/fcs ready (intra-wave: cheap)

  // ---- eig 1 ----
  jacobi8p(a, u, e, base);
  float lam = sel8(a, e);
  float sw = sqrtf(fmaxf(lam, EPSV));
  // row e of V = U^T w2, scaled by sqrt(clamped eig)
#pragma unroll
  for (int j = 0; j < 8; ++j) v[j] = 0.f;
#pragma unroll
  for (int i = 0; i < 8; ++i)
#pragma unroll
    for (int j = 0; j < 8; ++j) v[j] = fmaf(u[i], w2s[i * 8 + j], v[j]);
#pragma unroll
  for (int j = 0; j < 8; ++j) Wg[e * 8 + j] = v[j] * sw;
  __syncthreads();
  // M2 column e: m2[i] = sum_k W[k][i] * W[k][e]
  {
    float wcol[8];
#pragma unroll
    for (int k = 0; k < 8; ++k) wcol[k] = Wg[k * 8 + e];
#pragma unroll
    for (int i = 0; i < 8; ++i) m2[i] = 0.f;
#pragma unroll
    for (int k = 0; k < 8; ++k) {
      float4 q0 = *(const float4*)&Wg[k * 8 + 0];
      float4 q1 = *(const float4*)&Wg[k * 8 + 4];
      m2[0] = fmaf(q0.x, wcol[k], m2[0]); m2[1] = fmaf(q0.y, wcol[k], m2[1]);
      m2[2] = fmaf(q0.z, wcol[k], m2[2]); m2[3] = fmaf(q0.w, wcol[k], m2[3]);
      m2[4] = fmaf(q1.x, wcol[k], m2[4]); m2[5] = fmaf(q1.y, wcol[k], m2[5]);
      m2[6] = fmaf(q1.z, wcol[k], m2[6]); m2[7] = fmaf(q1.w, wcol[k], m2[7]);
    }
  }
  __syncthreads();  // Wbuf reads done before reuse

  // ---- eig 2 + fused rec+logm ----
#pragma unroll
  for (int i = 0; i < 8; ++i) a[i] = m2[i];
  jacobi8p(a, u, e, base);
  float lw = logf(fmaxf(sel8(a, e), EPSV));
#pragma unroll
  for (int i = 0; i < 8; ++i) Wg[e * 8 + i] = u[i];
  lwbuf[g * 8 + e] = lw;
  __syncthreads();
  // feat column e: fcol[i] = sum_k lw_k * T[k][i] * T[k][e]
  {
    float mk[8];
#pragma unroll
    for (int k = 0; k < 8; ++k) mk[k] = lwbuf[g * 8 + k] * Wg[k * 8 + e];
    float fcol[8];
#pragma unroll
    for (int i = 0; i < 8; ++i) fcol[i] = 0.f;
#pragma unroll
    for (int k = 0; k < 8; ++k) {
      float4 q0 = *(const float4*)&Wg[k * 8 + 0];
      float4 q1 = *(const float4*)&Wg[k * 8 + 4];
      fcol[0] = fmaf(q0.x, mk[k], fcol[0]); fcol[1] = fmaf(q0.y, mk[k], fcol[1]);
      fcol[2] = fmaf(q0.z, mk[k], fcol[2]); fcol[3] = fmaf(q0.w, mk[k], fcol[3]);
      fcol[4] = fmaf(q1.x, mk[k], fcol[4]); fcol[5] = fmaf(q1.y, mk[k], fcol[5]);
      fcol[6] = fmaf(q1.z, mk[k], fcol[6]); fcol[7] = fmaf(q1.w, mk[k], fcol[7]);
    }
    float l0 = 0.f, l1 = 0.f;
    float* featg = out + 2 * (size_t)B_TOTAL + (size_t)b * 64;
#pragma unroll
    for (int i = 0; i < 8; ++i) {
      featg[i * 8 + e] = fcol[i];
      l0 = fmaf(fcol[i], fcs[(i * 8 + e) * 2 + 0], l0);
      l1 = fmaf(fcol[i], fcs[(i * 8 + e) * 2 + 1], l1);
    }
#pragma unroll
    for (int mm = 1; mm < 8; mm <<= 1) {
      l0 += __shfl_xor(l0, mm);
      l1 += __shfl_xor(l1, mm);
    }
    float mx = fmaxf(l0, l1);
    float lse = mx + logf(expf(l0 - mx) + expf(l1 - mx));
    if (e < 2) out[(size_t)b * 2 + e] = (e ? l1 : l0) - lse;
  }
}

extern "C" void kernel_launch(void* const* d_in, const int* in_sizes, int n_in,
                              void* d_out, int out_size, void* d_ws, size_t ws_size,
                              hipStream_t stream) {
  const float* X  = (const float*)d_in[0];   // [8192,62,62]
  const float* w1 = (const float*)d_in[1];   // [62,8]
  const float* w2 = (const float*)d_in[2];   // [8,8]
  const float* fc = (const float*)d_in[3];   // [64,2]
  float* out = (float*)d_out;                // [8192*2] ++ [8192*64]
  float* M1 = (float*)d_ws;                  // 8192*64 floats = 2 MB

  bimap1_kernel<<<B_TOTAL, 64, 0, stream>>>(X, w1, M1);
  spd_eig8_kernel<<<B_TOTAL / 8, 64, 0, stream>>>(M1, w2, fc, out);
}